// Round 2
// baseline (1046.314 us; speedup 1.0000x reference)
//
#include <hip/hip_runtime.h>
#include <hip/hip_bf16.h>
#include <math.h>

// Problem constants
#define NF 172
#define TF_ 100
#define EF 172
#define EDIM 272      // query/embed dim
#define KD 444        // kv dim
#define NNB 20        // neighbors
#define HD 136        // head dim
#define OUT_D 172

// ---------------------------------------------------------------------------
// K0: sniff mask dtype. flag: 0 = int32, 1 = uint8, 2 = float32
// ---------------------------------------------------------------------------
__global__ void sniff_k(const unsigned char* __restrict__ m, int* __restrict__ flag) {
    __shared__ int c1, c2;
    if (threadIdx.x == 0) { c1 = 0; c2 = 0; }
    __syncthreads();
    for (int k = 0; k < 4; ++k) {
        int p = threadIdx.x * 4 + k;      // bytes 0..1023 (mask >= 640KB in any dtype)
        unsigned char v = m[p];
        if ((p & 3) != 0 && v)          atomicOr(&c1, 1);
        if ((p & 3) == 3 && v == 0x3f)  atomicOr(&c2, 1);
    }
    __syncthreads();
    if (threadIdx.x == 0) flag[0] = c2 ? 2 : (c1 ? 1 : 0);
}

// ---------------------------------------------------------------------------
// Generic fp32 GEMM: C[r, n] = act( sum_k A[r,k] * W(n,k) + bias[n] ) * live(r)
//   A = concat(A0[:,0:a0_cols], A1[:,...]) along k
//   W layout: w_nn==0 -> W[N][K] row-major (apply W^T), w_nn==1 -> W[K][N]
//   BM=BN=128, BK=16, 256 threads, 8x8 per thread.
//   Requires: M % 128 == 0, a0_cols % 4 == 0, strides % 4 == 0.
// ---------------------------------------------------------------------------
#define BM 128
#define BN 128
#define BK 16

__global__ __launch_bounds__(256) void gemm_k(
    const float* __restrict__ A0, int a0_cols, int a0_stride,
    const float* __restrict__ A1, int a1_stride,
    const float* __restrict__ W, int w_stride, int w_nn,
    const float* __restrict__ bias,
    const float* __restrict__ invalf,
    int relu,
    float* __restrict__ C, int c_stride,
    int N, int K)
{
    __shared__ float As[BK][BM];
    __shared__ float Ws[BK][BN];
    const int tid = threadIdx.x;
    const int tx = tid & 15, ty = tid >> 4;
    const int m0 = blockIdx.x * BM;
    const int n0 = blockIdx.y * BN;

    float acc[8][8];
#pragma unroll
    for (int i = 0; i < 8; ++i)
#pragma unroll
        for (int j = 0; j < 8; ++j) acc[i][j] = 0.f;

    const int arow = tid >> 1;        // 0..127
    const int akk  = (tid & 1) * 8;   // 0 or 8
    const int ktiles = (K + BK - 1) / BK;

    for (int t = 0; t < ktiles; ++t) {
        const int k0 = t * BK;
        // ---- A tile (transposed store) ----
        {
            const int r = m0 + arow;
#pragma unroll
            for (int half = 0; half < 2; ++half) {
                const int k = k0 + akk + half * 4;
                float4 v = make_float4(0.f, 0.f, 0.f, 0.f);
                if (k + 3 < K) {
                    const float* p = (k < a0_cols)
                        ? (A0 + (size_t)r * a0_stride + k)
                        : (A1 + (size_t)r * a1_stride + (k - a0_cols));
                    v = *(const float4*)p;
                }
                As[akk + half * 4 + 0][arow] = v.x;
                As[akk + half * 4 + 1][arow] = v.y;
                As[akk + half * 4 + 2][arow] = v.z;
                As[akk + half * 4 + 3][arow] = v.w;
            }
        }
        // ---- W tile ----
        if (!w_nn) {
            const int ncol = arow;
#pragma unroll
            for (int half = 0; half < 2; ++half) {
                const int k = k0 + akk + half * 4;
                float4 v = make_float4(0.f, 0.f, 0.f, 0.f);
                if ((n0 + ncol) < N && (k + 3) < K)
                    v = *(const float4*)(W + (size_t)(n0 + ncol) * w_stride + k);
                Ws[akk + half * 4 + 0][ncol] = v.x;
                Ws[akk + half * 4 + 1][ncol] = v.y;
                Ws[akk + half * 4 + 2][ncol] = v.z;
                Ws[akk + half * 4 + 3][ncol] = v.w;
            }
        } else {
            const int kk = tid >> 4;          // 0..15
            const int nb = (tid & 15) * 8;    // 0..120
#pragma unroll
            for (int half = 0; half < 2; ++half) {
                const int n = n0 + nb + half * 4;
                float4 v = make_float4(0.f, 0.f, 0.f, 0.f);
                if ((k0 + kk) < K && (n + 3) < N)
                    v = *(const float4*)(W + (size_t)(k0 + kk) * w_stride + n);
                *(float4*)&Ws[kk][nb + half * 4] = v;
            }
        }
        __syncthreads();
#pragma unroll
        for (int kk = 0; kk < BK; ++kk) {
            float4 a0v = *(const float4*)&As[kk][ty * 8];
            float4 a1v = *(const float4*)&As[kk][ty * 8 + 4];
            float4 b0v = *(const float4*)&Ws[kk][tx * 8];
            float4 b1v = *(const float4*)&Ws[kk][tx * 8 + 4];
            float a[8] = {a0v.x, a0v.y, a0v.z, a0v.w, a1v.x, a1v.y, a1v.z, a1v.w};
            float b[8] = {b0v.x, b0v.y, b0v.z, b0v.w, b1v.x, b1v.y, b1v.z, b1v.w};
#pragma unroll
            for (int i = 0; i < 8; ++i)
#pragma unroll
                for (int j = 0; j < 8; ++j)
                    acc[i][j] = fmaf(a[i], b[j], acc[i][j]);
        }
        __syncthreads();
    }

    // ---- epilogue ----
    float bv[8];
#pragma unroll
    for (int j = 0; j < 8; ++j) {
        const int n = n0 + tx * 8 + j;
        bv[j] = (bias && n < N) ? bias[n] : 0.f;
    }
#pragma unroll
    for (int i = 0; i < 8; ++i) {
        const int r = m0 + ty * 8 + i;
        float zf = 1.f;
        if (invalf && invalf[r] != 0.f) zf = 0.f;
#pragma unroll
        for (int half = 0; half < 2; ++half) {
            const int n = n0 + tx * 8 + half * 4;
            if (n + 3 < N) {
                float4 v;
                v.x = acc[i][half * 4 + 0] + bv[half * 4 + 0];
                v.y = acc[i][half * 4 + 1] + bv[half * 4 + 1];
                v.z = acc[i][half * 4 + 2] + bv[half * 4 + 2];
                v.w = acc[i][half * 4 + 3] + bv[half * 4 + 3];
                if (relu) {
                    v.x = fmaxf(v.x, 0.f); v.y = fmaxf(v.y, 0.f);
                    v.z = fmaxf(v.z, 0.f); v.w = fmaxf(v.w, 0.f);
                }
                v.x *= zf; v.y *= zf; v.z *= zf; v.w *= zf;
                *(float4*)(C + (size_t)r * c_stride + n) = v;
            }
        }
    }
}

// ---------------------------------------------------------------------------
// K3: fused attention pass. One block per batch row b.
//   Reads kv (nf|ef|ntf) once into LDS, qk[b,2,444]; computes masked scores,
//   softmax per head, attn_weights (mean over heads) -> d_out region 2,
//   wkv[b,h,:] = sum_n attn[h,n]*kv[n,:] -> ws (aliases qk), inval flag.
// ---------------------------------------------------------------------------
__global__ __launch_bounds__(256) void attn_fused_k(
    const float* __restrict__ nf, const float* __restrict__ ef,
    const float* __restrict__ ntf,
    const unsigned char* __restrict__ maskp,
    const int* __restrict__ mode_p,
    const float* __restrict__ qk,
    float* __restrict__ wkv,
    float* __restrict__ invalf,
    float* __restrict__ attnw)
{
    __shared__ float kvb[NNB * KD];   // 20*444
    __shared__ float qkb[2 * KD];     // 888
    __shared__ float sc[2][NNB];
    __shared__ float at[2][NNB];
    __shared__ int   msk[NNB];

    const int b = blockIdx.x;
    const int tid = threadIdx.x;
    const int lane = tid & 63;
    const int wv = tid >> 6;
    const int mode = mode_p[0];

    if (tid < 222)
        *(float4*)&qkb[tid * 4] = *(const float4*)(qk + (size_t)b * 888 + tid * 4);

    if (tid < NNB) {
        int mv;
        if (mode == 0)      mv = ((const int*)maskp)[b * NNB + tid] != 0;
        else if (mode == 1) mv = maskp[b * NNB + tid] != 0;
        else                mv = ((const float*)maskp)[b * NNB + tid] != 0.f;
        msk[tid] = mv;
    }

    // kv load: wave wv handles neighbors wv*5 .. wv*5+4; 111 float4 chunks/row
#pragma unroll
    for (int s = 0; s < 5; ++s) {
        const int n = wv * 5 + s;
        const size_t base = (size_t)(b * NNB + n);
        for (int c = lane; c < 111; c += 64) {
            float4 v;
            if (c < 43)      v = *(const float4*)(nf  + base * NF  + c * 4);
            else if (c < 86) v = *(const float4*)(ef  + base * EF  + (c - 43) * 4);
            else             v = *(const float4*)(ntf + base * TF_ + (c - 86) * 4);
            *(float4*)&kvb[n * KD + c * 4] = v;
        }
    }
    __syncthreads();

    if (tid == 0) {
        int inv = 1;
        for (int n = 0; n < NNB; ++n) inv &= msk[n];
        if (inv) msk[0] = 0;
        invalf[b] = (float)inv;
    }
    __syncthreads();

    // scores: wave per 5 neighbors, two heads at once
    const float scal = 0.08574929257125441f;  // 1/sqrt(136)
#pragma unroll
    for (int s = 0; s < 5; ++s) {
        const int n = wv * 5 + s;
        float p0 = 0.f, p1 = 0.f;
#pragma unroll
        for (int jj = 0; jj < 2; ++jj) {
            const int c = lane + jj * 64;
            if (c < 111) {
                float4 kvv = *(const float4*)&kvb[n * KD + c * 4];
                float4 q0  = *(const float4*)&qkb[c * 4];
                float4 q1  = *(const float4*)&qkb[KD + c * 4];
                p0 += q0.x * kvv.x + q0.y * kvv.y + q0.z * kvv.z + q0.w * kvv.w;
                p1 += q1.x * kvv.x + q1.y * kvv.y + q1.z * kvv.z + q1.w * kvv.w;
            }
        }
#pragma unroll
        for (int off = 32; off; off >>= 1) {
            p0 += __shfl_xor(p0, off);
            p1 += __shfl_xor(p1, off);
        }
        if (lane == 0) {
            const int m = msk[n];
            sc[0][n] = m ? -1e30f : p0 * scal;
            sc[1][n] = m ? -1e30f : p1 * scal;
        }
    }
    __syncthreads();

    if (tid < 2) {
        const int h = tid;
        float mx = -3.4e38f;
        for (int n = 0; n < NNB; ++n) mx = fmaxf(mx, sc[h][n]);
        float sm = 0.f;
        for (int n = 0; n < NNB; ++n) {
            const float e = expf(sc[h][n] - mx);
            at[h][n] = e;
            sm += e;
        }
        const float r = 1.f / sm;
        for (int n = 0; n < NNB; ++n) at[h][n] *= r;
    }
    __syncthreads();

    if (tid < NNB)
        attnw[(size_t)b * NNB + tid] = 0.5f * (at[0][tid] + at[1][tid]);

    if (tid < 222) {
        const int h = (tid < 111) ? 0 : 1;
        const int il = (tid - h * 111) * 4;   // local offset within head's 444
        float4 acc = make_float4(0.f, 0.f, 0.f, 0.f);
#pragma unroll
        for (int n = 0; n < NNB; ++n) {
            const float w = at[h][n];
            float4 kvv = *(const float4*)&kvb[n * KD + il];
            acc.x = fmaf(w, kvv.x, acc.x);
            acc.y = fmaf(w, kvv.y, acc.y);
            acc.z = fmaf(w, kvv.z, acc.z);
            acc.w = fmaf(w, kvv.w, acc.w);
        }
        *(float4*)(wkv + (size_t)b * 888 + tid * 4) = acc;
    }
}

// ---------------------------------------------------------------------------
extern "C" void kernel_launch(void* const* d_in, const int* in_sizes, int n_in,
                              void* d_out, int out_size, void* d_ws, size_t ws_size,
                              hipStream_t stream) {
    const float* src_node = (const float*)d_in[0];
    const float* src_time = (const float*)d_in[1];
    const float* nfp      = (const float*)d_in[2];
    const float* ntfp     = (const float*)d_in[3];  // neighbor_time
    const float* efp      = (const float*)d_in[4];  // edge
    const unsigned char* maskp = (const unsigned char*)d_in[5];
    const float* q_w   = (const float*)d_in[6];
    const float* k_w   = (const float*)d_in[7];
    const float* v_w   = (const float*)d_in[8];
    const float* q_b   = (const float*)d_in[9];
    // d_in[10] = k_b: provably no effect on outputs (uniform shift under softmax)
    const float* v_b   = (const float*)d_in[11];
    const float* out_w = (const float*)d_in[12];
    const float* out_b = (const float*)d_in[13];
    const float* m1_w  = (const float*)d_in[14];
    const float* m1_b  = (const float*)d_in[15];
    const float* m2_w  = (const float*)d_in[16];
    const float* m2_b  = (const float*)d_in[17];

    const int B = in_sizes[0] / NF;   // 32768

    // ws layout (aliasing, stream-ordered safe):
    //   flag [16]  | Qb [B,272] (Q -> ctx -> hidden) | qkb [B,888] (qk -> wkv -> attn_out) | invb [B]
    float* ws   = (float*)d_ws;
    int*   flag = (int*)d_ws;
    float* Qb   = ws + 16;                       // [B,272]
    float* qkb  = Qb + (size_t)B * 272;          // [B,2,444]
    float* invb = qkb + (size_t)B * 888;         // [B]
    float* aob  = qkb;                           // [B,272] attn_out (reuse qkb after K5)
    float* hidb = Qb;                            // [B,172] hidden  (reuse Qb after K6)
    float* outp  = (float*)d_out;                // [B,172]
    float* attnw = outp + (size_t)B * OUT_D;     // [B,20]

    const int gm = B / BM;   // 256

    sniff_k<<<1, 256, 0, stream>>>(maskp, flag);

    // K1: Q = concat(src_node, src_time) @ q_w.T + q_b       [B,272]
    gemm_k<<<dim3(gm, 3), 256, 0, stream>>>(
        src_node, NF, NF, src_time, TF_,
        q_w, EDIM, 0, q_b, nullptr, 0, Qb, EDIM, EDIM, EDIM);

    // K2 (h=0,1): qk[:,h,:] = Q[:,h*136:(h+1)*136] @ k_w[h*136:,:]   [B,444]
    for (int h = 0; h < 2; ++h) {
        gemm_k<<<dim3(gm, 4), 256, 0, stream>>>(
            Qb + h * HD, HD, EDIM, nullptr, 0,
            k_w + (size_t)h * HD * KD, KD, 1, nullptr, nullptr, 0,
            qkb + h * KD, 888, KD, HD);
    }

    // K3: fused scores/softmax/attn_weights/wkv (wkv aliases qk)
    attn_fused_k<<<B, 256, 0, stream>>>(nfp, efp, ntfp, maskp, flag,
                                        qkb, qkb, invb, attnw);

    // K5 (h=0,1): ctx[:,h*136:] = wkv[:,h,:] @ v_w[h-part].T + v_b   (ctx = Qb)
    for (int h = 0; h < 2; ++h) {
        gemm_k<<<dim3(gm, 2), 256, 0, stream>>>(
            qkb + h * KD, KD, 888, nullptr, 0,
            v_w + (size_t)h * HD * KD, KD, 0, v_b + h * HD, nullptr, 0,
            Qb + h * HD, EDIM, HD, KD);
    }

    // K6: attn_out = ctx @ out_w.T + out_b, zeroed where invalid (-> qkb region)
    gemm_k<<<dim3(gm, 3), 256, 0, stream>>>(
        Qb, EDIM, EDIM, nullptr, 0,
        out_w, EDIM, 0, out_b, invb, 0, aob, EDIM, EDIM, EDIM);

    // K7: hidden = relu(concat(attn_out, src_node) @ m1_w.T + m1_b)  (-> Qb region)
    gemm_k<<<dim3(gm, 2), 256, 0, stream>>>(
        aob, EDIM, EDIM, src_node, NF,
        m1_w, KD, 0, m1_b, nullptr, 1, hidb, OUT_D, OUT_D, KD);

    // K8: out = hidden @ m2_w.T + m2_b
    gemm_k<<<dim3(gm, 2), 256, 0, stream>>>(
        hidb, OUT_D, OUT_D, nullptr, 0,
        m2_w, OUT_D, 0, m2_b, nullptr, 0, outp, OUT_D, OUT_D, OUT_D);
}

// Round 3
// 944.212 us; speedup vs baseline: 1.1081x; 1.1081x over previous
//
#include <hip/hip_runtime.h>
#include <hip/hip_bf16.h>
#include <math.h>

// Problem constants
#define NF 172
#define TF_ 100
#define EF 172
#define EDIM 272      // query/embed dim
#define KD 444        // kv dim
#define NNB 20        // neighbors
#define HD 136        // head dim
#define OUT_D 172

// ---------------------------------------------------------------------------
// K0: sniff mask dtype. flag: 0 = int32, 1 = uint8, 2 = float32
// ---------------------------------------------------------------------------
__global__ void sniff_k(const unsigned char* __restrict__ m, int* __restrict__ flag) {
    __shared__ int c1, c2;
    if (threadIdx.x == 0) { c1 = 0; c2 = 0; }
    __syncthreads();
    for (int k = 0; k < 4; ++k) {
        int p = threadIdx.x * 4 + k;      // bytes 0..1023 (mask >= 640KB in any dtype)
        unsigned char v = m[p];
        if ((p & 3) != 0 && v)          atomicOr(&c1, 1);
        if ((p & 3) == 3 && v == 0x3f)  atomicOr(&c2, 1);
    }
    __syncthreads();
    if (threadIdx.x == 0) flag[0] = c2 ? 2 : (c1 ? 1 : 0);
}

// ---------------------------------------------------------------------------
// Generic fp32 GEMM (unchanged from round 2): C = act(A @ W(T) + b) * live
// ---------------------------------------------------------------------------
#define BM 128
#define BN 128
#define BK 16

__global__ __launch_bounds__(256) void gemm_k(
    const float* __restrict__ A0, int a0_cols, int a0_stride,
    const float* __restrict__ A1, int a1_stride,
    const float* __restrict__ W, int w_stride, int w_nn,
    const float* __restrict__ bias,
    const float* __restrict__ invalf,
    int relu,
    float* __restrict__ C, int c_stride,
    int N, int K)
{
    __shared__ float As[BK][BM];
    __shared__ float Ws[BK][BN];
    const int tid = threadIdx.x;
    const int tx = tid & 15, ty = tid >> 4;
    const int m0 = blockIdx.x * BM;
    const int n0 = blockIdx.y * BN;

    float acc[8][8];
#pragma unroll
    for (int i = 0; i < 8; ++i)
#pragma unroll
        for (int j = 0; j < 8; ++j) acc[i][j] = 0.f;

    const int arow = tid >> 1;        // 0..127
    const int akk  = (tid & 1) * 8;   // 0 or 8
    const int ktiles = (K + BK - 1) / BK;

    for (int t = 0; t < ktiles; ++t) {
        const int k0 = t * BK;
        {
            const int r = m0 + arow;
#pragma unroll
            for (int half = 0; half < 2; ++half) {
                const int k = k0 + akk + half * 4;
                float4 v = make_float4(0.f, 0.f, 0.f, 0.f);
                if (k + 3 < K) {
                    const float* p = (k < a0_cols)
                        ? (A0 + (size_t)r * a0_stride + k)
                        : (A1 + (size_t)r * a1_stride + (k - a0_cols));
                    v = *(const float4*)p;
                }
                As[akk + half * 4 + 0][arow] = v.x;
                As[akk + half * 4 + 1][arow] = v.y;
                As[akk + half * 4 + 2][arow] = v.z;
                As[akk + half * 4 + 3][arow] = v.w;
            }
        }
        if (!w_nn) {
            const int ncol = arow;
#pragma unroll
            for (int half = 0; half < 2; ++half) {
                const int k = k0 + akk + half * 4;
                float4 v = make_float4(0.f, 0.f, 0.f, 0.f);
                if ((n0 + ncol) < N && (k + 3) < K)
                    v = *(const float4*)(W + (size_t)(n0 + ncol) * w_stride + k);
                Ws[akk + half * 4 + 0][ncol] = v.x;
                Ws[akk + half * 4 + 1][ncol] = v.y;
                Ws[akk + half * 4 + 2][ncol] = v.z;
                Ws[akk + half * 4 + 3][ncol] = v.w;
            }
        } else {
            const int kk = tid >> 4;          // 0..15
            const int nb = (tid & 15) * 8;    // 0..120
#pragma unroll
            for (int half = 0; half < 2; ++half) {
                const int n = n0 + nb + half * 4;
                float4 v = make_float4(0.f, 0.f, 0.f, 0.f);
                if ((k0 + kk) < K && (n + 3) < N)
                    v = *(const float4*)(W + (size_t)(k0 + kk) * w_stride + n);
                *(float4*)&Ws[kk][nb + half * 4] = v;
            }
        }
        __syncthreads();
#pragma unroll
        for (int kk = 0; kk < BK; ++kk) {
            float4 a0v = *(const float4*)&As[kk][ty * 8];
            float4 a1v = *(const float4*)&As[kk][ty * 8 + 4];
            float4 b0v = *(const float4*)&Ws[kk][tx * 8];
            float4 b1v = *(const float4*)&Ws[kk][tx * 8 + 4];
            float a[8] = {a0v.x, a0v.y, a0v.z, a0v.w, a1v.x, a1v.y, a1v.z, a1v.w};
            float b[8] = {b0v.x, b0v.y, b0v.z, b0v.w, b1v.x, b1v.y, b1v.z, b1v.w};
#pragma unroll
            for (int i = 0; i < 8; ++i)
#pragma unroll
                for (int j = 0; j < 8; ++j)
                    acc[i][j] = fmaf(a[i], b[j], acc[i][j]);
        }
        __syncthreads();
    }

    float bv[8];
#pragma unroll
    for (int j = 0; j < 8; ++j) {
        const int n = n0 + tx * 8 + j;
        bv[j] = (bias && n < N) ? bias[n] : 0.f;
    }
#pragma unroll
    for (int i = 0; i < 8; ++i) {
        const int r = m0 + ty * 8 + i;
        float zf = 1.f;
        if (invalf && invalf[r] != 0.f) zf = 0.f;
#pragma unroll
        for (int half = 0; half < 2; ++half) {
            const int n = n0 + tx * 8 + half * 4;
            if (n + 3 < N) {
                float4 v;
                v.x = acc[i][half * 4 + 0] + bv[half * 4 + 0];
                v.y = acc[i][half * 4 + 1] + bv[half * 4 + 1];
                v.z = acc[i][half * 4 + 2] + bv[half * 4 + 2];
                v.w = acc[i][half * 4 + 3] + bv[half * 4 + 3];
                if (relu) {
                    v.x = fmaxf(v.x, 0.f); v.y = fmaxf(v.y, 0.f);
                    v.z = fmaxf(v.z, 0.f); v.w = fmaxf(v.w, 0.f);
                }
                v.x *= zf; v.y *= zf; v.z *= zf; v.w *= zf;
                *(float4*)(C + (size_t)r * c_stride + n) = v;
            }
        }
    }
}

// ---------------------------------------------------------------------------
// K3 (new): flash-style fused attention. ONE WAVE PER ROW, no LDS, no barriers.
//   Row's kv [20][444] is streamed once as per-lane float4 column slices:
//     chunk A: c4 = lane        (0..63)   -> nf (c4<43) | ef (c4-43)
//     chunk B: c4 = 64 + lane   (lane<47) -> ef (c4<86) | ntf (c4-86)
//   Scores via butterfly shfl_xor reduce; online softmax (running m, sum,
//   rescaled accumulators). Outputs wkv (normalized, aliases qk), attnw, inval.
// ---------------------------------------------------------------------------
__device__ __forceinline__ float dot4(float4 a, float4 b) {
    return a.x * b.x + a.y * b.y + a.z * b.z + a.w * b.w;
}

__global__ __launch_bounds__(256) void attn_flash_k(
    const float* __restrict__ nf, const float* __restrict__ ef,
    const float* __restrict__ ntf,
    const unsigned char* __restrict__ maskp,
    const int* __restrict__ mode_p,
    const float* __restrict__ qk,
    float* __restrict__ wkv,
    float* __restrict__ invalf,
    float* __restrict__ attnw)
{
    const int lane = threadIdx.x & 63;
    const int wv   = threadIdx.x >> 6;
    const int b    = blockIdx.x * 4 + wv;
    const int mode = mode_p[0];

    // ---- mask (lane n<20 holds its neighbor's mask bit) ----
    int mv = 0;
    if (lane < NNB) {
        if (mode == 0)      mv = ((const int*)maskp)[(size_t)b * NNB + lane] != 0;
        else if (mode == 1) mv = maskp[(size_t)b * NNB + lane] != 0;
        else                mv = ((const float*)maskp)[(size_t)b * NNB + lane] != 0.f;
    }
    unsigned long long bal = __ballot(lane < NNB && mv);
    const int inv = ((bal & 0xFFFFFULL) == 0xFFFFFULL);
    if (inv && lane == 0) mv = 0;            // force-unmask neighbor 0
    if (lane == 0) invalf[b] = (float)inv;

    // ---- q fragments (both heads, 2 chunks each) ----
    const float* qrow = qk + (size_t)b * 888;
    const float4 z4 = make_float4(0.f, 0.f, 0.f, 0.f);
    float4 q0a = *(const float4*)(qrow + lane * 4);
    float4 q1a = *(const float4*)(qrow + KD + lane * 4);
    float4 q0b = z4, q1b = z4;
    if (lane < 47) {
        q0b = *(const float4*)(qrow + (64 + lane) * 4);
        q1b = *(const float4*)(qrow + KD + (64 + lane) * 4);
    }

    // ---- per-lane kv pointers ----
    const size_t rbase = (size_t)b * NNB;
    const float* pA;                 // chunk A, stride 172 (nf and ef rows both 172)
    if (lane < 43) pA = nf + rbase * NF + lane * 4;
    else           pA = ef + rbase * EF + (lane - 43) * 4;
    const float* pB;                 // chunk B (lanes < 47)
    int strideB;
    if (lane < 22) { pB = ef  + rbase * EF  + (21 + lane) * 4; strideB = EF;  }
    else           { pB = ntf + rbase * TF_ + (lane - 22) * 4; strideB = TF_; }

    // ---- online softmax state ----
    const float scal = 0.08574929257125441f;  // 1/sqrt(136)
    float4 acc0a = z4, acc0b = z4, acc1a = z4, acc1b = z4;
    float m0 = -3.4e38f, m1 = -3.4e38f, s0 = 0.f, s1 = 0.f;
    float mys0 = 0.f, mys1 = 0.f;             // this lane's neighbor score (n==lane)

#pragma unroll 5
    for (int n = 0; n < NNB; ++n) {
        float4 kA = *(const float4*)pA;
        pA += NF;
        float4 kB = z4;
        if (lane < 47) {
            kB = *(const float4*)pB;
            pB += strideB;
        }

        float p0 = dot4(q0a, kA) + dot4(q0b, kB);
        float p1 = dot4(q1a, kA) + dot4(q1b, kB);
#pragma unroll
        for (int off = 32; off; off >>= 1) {
            p0 += __shfl_xor(p0, off);
            p1 += __shfl_xor(p1, off);
        }

        const int mn = __shfl(mv, n);
        const float sc0 = mn ? -1e30f : p0 * scal;
        const float sc1 = mn ? -1e30f : p1 * scal;
        if (lane == n) { mys0 = sc0; mys1 = sc1; }

        // head 0 online update
        {
            const float nm = fmaxf(m0, sc0);
            const float f  = expf(m0 - nm);     // rescale (==1 when no new max)
            const float p  = expf(sc0 - nm);
            s0 = s0 * f + p;
            acc0a.x = acc0a.x * f + p * kA.x;  acc0a.y = acc0a.y * f + p * kA.y;
            acc0a.z = acc0a.z * f + p * kA.z;  acc0a.w = acc0a.w * f + p * kA.w;
            acc0b.x = acc0b.x * f + p * kB.x;  acc0b.y = acc0b.y * f + p * kB.y;
            acc0b.z = acc0b.z * f + p * kB.z;  acc0b.w = acc0b.w * f + p * kB.w;
            m0 = nm;
        }
        // head 1 online update
        {
            const float nm = fmaxf(m1, sc1);
            const float f  = expf(m1 - nm);
            const float p  = expf(sc1 - nm);
            s1 = s1 * f + p;
            acc1a.x = acc1a.x * f + p * kA.x;  acc1a.y = acc1a.y * f + p * kA.y;
            acc1a.z = acc1a.z * f + p * kA.z;  acc1a.w = acc1a.w * f + p * kA.w;
            acc1b.x = acc1b.x * f + p * kB.x;  acc1b.y = acc1b.y * f + p * kB.y;
            acc1b.z = acc1b.z * f + p * kB.z;  acc1b.w = acc1b.w * f + p * kB.w;
            m1 = nm;
        }
    }

    const float r0 = 1.f / s0;
    const float r1 = 1.f / s1;

    // ---- attn_weights (mean over heads) ----
    if (lane < NNB)
        attnw[(size_t)b * NNB + lane] =
            0.5f * (expf(mys0 - m0) * r0 + expf(mys1 - m1) * r1);

    // ---- normalized wkv store ----
    float* wrow = wkv + (size_t)b * 888;
    float4 o;
    o.x = acc0a.x * r0; o.y = acc0a.y * r0; o.z = acc0a.z * r0; o.w = acc0a.w * r0;
    *(float4*)(wrow + lane * 4) = o;
    o.x = acc1a.x * r1; o.y = acc1a.y * r1; o.z = acc1a.z * r1; o.w = acc1a.w * r1;
    *(float4*)(wrow + KD + lane * 4) = o;
    if (lane < 47) {
        o.x = acc0b.x * r0; o.y = acc0b.y * r0; o.z = acc0b.z * r0; o.w = acc0b.w * r0;
        *(float4*)(wrow + (64 + lane) * 4) = o;
        o.x = acc1b.x * r1; o.y = acc1b.y * r1; o.z = acc1b.z * r1; o.w = acc1b.w * r1;
        *(float4*)(wrow + KD + (64 + lane) * 4) = o;
    }
}

// ---------------------------------------------------------------------------
extern "C" void kernel_launch(void* const* d_in, const int* in_sizes, int n_in,
                              void* d_out, int out_size, void* d_ws, size_t ws_size,
                              hipStream_t stream) {
    const float* src_node = (const float*)d_in[0];
    const float* src_time = (const float*)d_in[1];
    const float* nfp      = (const float*)d_in[2];
    const float* ntfp     = (const float*)d_in[3];  // neighbor_time
    const float* efp      = (const float*)d_in[4];  // edge
    const unsigned char* maskp = (const unsigned char*)d_in[5];
    const float* q_w   = (const float*)d_in[6];
    const float* k_w   = (const float*)d_in[7];
    const float* v_w   = (const float*)d_in[8];
    const float* q_b   = (const float*)d_in[9];
    // d_in[10] = k_b: provably no effect on outputs (uniform shift under softmax)
    const float* v_b   = (const float*)d_in[11];
    const float* out_w = (const float*)d_in[12];
    const float* out_b = (const float*)d_in[13];
    const float* m1_w  = (const float*)d_in[14];
    const float* m1_b  = (const float*)d_in[15];
    const float* m2_w  = (const float*)d_in[16];
    const float* m2_b  = (const float*)d_in[17];

    const int B = in_sizes[0] / NF;   // 32768

    // ws layout (aliasing, stream-ordered safe):
    //   flag [16] | Qb [B,272] (Q -> ctx -> hidden) | qkb [B,888] (qk -> wkv -> attn_out) | invb [B]
    float* ws   = (float*)d_ws;
    int*   flag = (int*)d_ws;
    float* Qb   = ws + 16;                       // [B,272]
    float* qkb  = Qb + (size_t)B * 272;          // [B,2,444]
    float* invb = qkb + (size_t)B * 888;         // [B]
    float* aob  = qkb;                           // [B,272] attn_out (reuse qkb after K5)
    float* hidb = Qb;                            // [B,172] hidden  (reuse Qb after K6)
    float* outp  = (float*)d_out;                // [B,172]
    float* attnw = outp + (size_t)B * OUT_D;     // [B,20]

    const int gm = B / BM;   // 256

    sniff_k<<<1, 256, 0, stream>>>(maskp, flag);

    // K1: Q = concat(src_node, src_time) @ q_w.T + q_b       [B,272]
    gemm_k<<<dim3(gm, 3), 256, 0, stream>>>(
        src_node, NF, NF, src_time, TF_,
        q_w, EDIM, 0, q_b, nullptr, 0, Qb, EDIM, EDIM, EDIM);

    // K2 (h=0,1): qk[:,h,:] = Q[:,h*136:(h+1)*136] @ k_w[h*136:,:]   [B,444]
    for (int h = 0; h < 2; ++h) {
        gemm_k<<<dim3(gm, 4), 256, 0, stream>>>(
            Qb + h * HD, HD, EDIM, nullptr, 0,
            k_w + (size_t)h * HD * KD, KD, 1, nullptr, nullptr, 0,
            qkb + h * KD, 888, KD, HD);
    }

    // K3: flash attention pass (wkv aliases qk; same-row read-then-write in-wave)
    attn_flash_k<<<B / 4, 256, 0, stream>>>(nfp, efp, ntfp, maskp, flag,
                                            qkb, qkb, invb, attnw);

    // K5 (h=0,1): ctx[:,h*136:] = wkv[:,h,:] @ v_w[h-part].T + v_b   (ctx = Qb)
    for (int h = 0; h < 2; ++h) {
        gemm_k<<<dim3(gm, 2), 256, 0, stream>>>(
            qkb + h * KD, KD, 888, nullptr, 0,
            v_w + (size_t)h * HD * KD, KD, 0, v_b + h * HD, nullptr, 0,
            Qb + h * HD, EDIM, HD, KD);
    }

    // K6: attn_out = ctx @ out_w.T + out_b, zeroed where invalid (-> qkb region)
    gemm_k<<<dim3(gm, 3), 256, 0, stream>>>(
        Qb, EDIM, EDIM, nullptr, 0,
        out_w, EDIM, 0, out_b, invb, 0, aob, EDIM, EDIM, EDIM);

    // K7: hidden = relu(concat(attn_out, src_node) @ m1_w.T + m1_b)  (-> Qb region)
    gemm_k<<<dim3(gm, 2), 256, 0, stream>>>(
        aob, EDIM, EDIM, src_node, NF,
        m1_w, KD, 0, m1_b, nullptr, 1, hidb, OUT_D, OUT_D, KD);

    // K8: out = hidden @ m2_w.T + m2_b
    gemm_k<<<dim3(gm, 2), 256, 0, stream>>>(
        hidb, OUT_D, OUT_D, nullptr, 0,
        m2_w, OUT_D, 0, m2_b, nullptr, 0, outp, OUT_D, OUT_D, OUT_D);
}

// Round 4
// 691.693 us; speedup vs baseline: 1.5127x; 1.3651x over previous
//
#include <hip/hip_runtime.h>
#include <hip/hip_bf16.h>
#include <math.h>

// Problem constants
#define NF 172
#define TF_ 100
#define EF 172
#define EDIM 272      // query/embed dim
#define KD 444        // kv dim
#define NNB 20        // neighbors
#define HD 136        // head dim
#define OUT_D 172

typedef __attribute__((ext_vector_type(4))) float f32x4;
typedef __attribute__((ext_vector_type(8))) __bf16 bf16x8;
typedef __attribute__((ext_vector_type(4))) __bf16 bf16x4;

// ---------------------------------------------------------------------------
// K0: sniff mask dtype. flag: 0 = int32, 1 = uint8, 2 = float32
// ---------------------------------------------------------------------------
__global__ void sniff_k(const unsigned char* __restrict__ m, int* __restrict__ flag) {
    __shared__ int c1, c2;
    if (threadIdx.x == 0) { c1 = 0; c2 = 0; }
    __syncthreads();
    for (int k = 0; k < 4; ++k) {
        int p = threadIdx.x * 4 + k;      // bytes 0..1023 (mask >= 640KB in any dtype)
        unsigned char v = m[p];
        if ((p & 3) != 0 && v)          atomicOr(&c1, 1);
        if ((p & 3) == 3 && v == 0x3f)  atomicOr(&c2, 1);
    }
    __syncthreads();
    if (threadIdx.x == 0) flag[0] = c2 ? 2 : (c1 ? 1 : 0);
}

// ---------------------------------------------------------------------------
// bf16-MFMA GEMM: C[r,n] = act( sum_k A[r,k]*W(n,k) + bias[n] ) * live(r)
//   A fp32 = concat(A0[:,0:a0_cols], A1) along k; converted to bf16 on stage.
//   W fp32: w_nn==0 -> W[N][K] (apply W^T), w_nn==1 -> W[K][N].
//   Tile 128x128, BK=32, 256 thr = 4 waves, each wave 64x64 (4x4 frags of
//   16x16x32). LDS operand-major [dim][40] bf16 (pad -> 16B-aligned b128).
//   MFMA frag layout: A row=l&15,k=8*(l>>4)+j ; B col=l&15,k=8*(l>>4)+j ;
//   D col=l&15,row=4*(l>>4)+reg (m89-verified).
//   Requires M%128==0, K%4==0, a0_cols%4==0.
// ---------------------------------------------------------------------------
#define BKP 40   // padded k-stride in LDS (shorts)

__global__ __launch_bounds__(256) void gemm_mfma_k(
    const float* __restrict__ A0, int a0_cols, int a0_stride,
    const float* __restrict__ A1, int a1_stride,
    const float* __restrict__ W, int w_stride, int w_nn,
    const float* __restrict__ bias,
    const float* __restrict__ invalf,
    int relu,
    float* __restrict__ C, int c_stride,
    int N, int K)
{
    __shared__ __bf16 As[128][BKP];
    __shared__ __bf16 Bs[128][BKP];

    const int tid  = threadIdx.x;
    const int lane = tid & 63;
    const int wv   = tid >> 6;
    const int wr   = wv >> 1;          // 0..1 : wave row (64-row half)
    const int wc   = wv & 1;           // 0..1 : wave col (64-col half)
    const int lr   = lane & 15;        // fragment row/col
    const int lg   = lane >> 4;        // k-group (0..3)
    const int m0   = blockIdx.x * 128;
    const int n0   = blockIdx.y * 128;

    f32x4 acc[4][4];
#pragma unroll
    for (int i = 0; i < 4; ++i)
#pragma unroll
        for (int j = 0; j < 4; ++j) acc[i][j] = (f32x4)(0.f);

    // staging roles
    const int srow = tid >> 1;             // 0..127 (A row / B col for w_nn==0)
    const int sch0 = (tid & 1) * 4;        // chunk base (chunks of 4 k)
    const int tkk  = tid >> 3;             // 0..31 (w_nn==1: k row)
    const int tcb  = (tid & 7) * 16;       // w_nn==1: col base (4 float4s)

    const int ktiles = (K + 31) / 32;

    for (int t = 0; t < ktiles; ++t) {
        const int k0 = t * 32;

        // ---- stage A tile: [row][k] fp32 -> bf16 ----
#pragma unroll
        for (int i = 0; i < 4; ++i) {
            const int ch = sch0 + i;           // 0..7
            const int k  = k0 + ch * 4;
            float4 v = make_float4(0.f, 0.f, 0.f, 0.f);
            if (k < K) {
                const float* p = (k < a0_cols)
                    ? (A0 + (size_t)(m0 + srow) * a0_stride + k)
                    : (A1 + (size_t)(m0 + srow) * a1_stride + (k - a0_cols));
                v = *(const float4*)p;
            }
            bf16x4 b;
            b[0] = (__bf16)v.x; b[1] = (__bf16)v.y;
            b[2] = (__bf16)v.z; b[3] = (__bf16)v.w;
            *(bf16x4*)&As[srow][ch * 4] = b;
        }

        // ---- stage B tile -> Bs[col][k] ----
        if (!w_nn) {
            // W[N][K]: row n gives contiguous k
#pragma unroll
            for (int i = 0; i < 4; ++i) {
                const int ch = sch0 + i;
                const int k  = k0 + ch * 4;
                float4 v = make_float4(0.f, 0.f, 0.f, 0.f);
                if (k < K && (n0 + srow) < N)
                    v = *(const float4*)(W + (size_t)(n0 + srow) * w_stride + k);
                bf16x4 b;
                b[0] = (__bf16)v.x; b[1] = (__bf16)v.y;
                b[2] = (__bf16)v.z; b[3] = (__bf16)v.w;
                *(bf16x4*)&Bs[srow][ch * 4] = b;
            }
        } else {
            // W[K][N]: transpose during store (scalar bf16 writes)
#pragma unroll
            for (int i = 0; i < 4; ++i) {
                const int c = tcb + i * 4;
                float4 v = make_float4(0.f, 0.f, 0.f, 0.f);
                if ((k0 + tkk) < K && (n0 + c + 3) < N)
                    v = *(const float4*)(W + (size_t)(k0 + tkk) * w_stride + n0 + c);
                Bs[c + 0][tkk] = (__bf16)v.x;
                Bs[c + 1][tkk] = (__bf16)v.y;
                Bs[c + 2][tkk] = (__bf16)v.z;
                Bs[c + 3][tkk] = (__bf16)v.w;
            }
        }
        __syncthreads();

        // ---- fragments + MFMA ----
        bf16x8 af[4], bfr[4];
#pragma unroll
        for (int f = 0; f < 4; ++f) {
            af[f]  = *(const bf16x8*)&As[wr * 64 + f * 16 + lr][lg * 8];
            bfr[f] = *(const bf16x8*)&Bs[wc * 64 + f * 16 + lr][lg * 8];
        }
#pragma unroll
        for (int fm = 0; fm < 4; ++fm)
#pragma unroll
            for (int fn = 0; fn < 4; ++fn)
                acc[fm][fn] = __builtin_amdgcn_mfma_f32_16x16x32_bf16(
                    af[fm], bfr[fn], acc[fm][fn], 0, 0, 0);
        __syncthreads();
    }

    // ---- epilogue: D col=l&15, row=4*(l>>4)+reg ----
    float bv[4];
#pragma unroll
    for (int fn = 0; fn < 4; ++fn) {
        const int col = n0 + wc * 64 + fn * 16 + lr;
        bv[fn] = (bias && col < N) ? bias[col] : 0.f;
    }
#pragma unroll
    for (int fm = 0; fm < 4; ++fm) {
#pragma unroll
        for (int j = 0; j < 4; ++j) {
            const int row = m0 + wr * 64 + fm * 16 + lg * 4 + j;
            float zf = 1.f;
            if (invalf && invalf[row] != 0.f) zf = 0.f;
#pragma unroll
            for (int fn = 0; fn < 4; ++fn) {
                const int col = n0 + wc * 64 + fn * 16 + lr;
                if (col < N) {
                    float v = acc[fm][fn][j] + bv[fn];
                    if (relu) v = fmaxf(v, 0.f);
                    C[(size_t)row * c_stride + col] = v * zf;
                }
            }
        }
    }
}

// ---------------------------------------------------------------------------
// K3: flash-style fused attention. One wave per row, no LDS, no barriers.
// ---------------------------------------------------------------------------
__device__ __forceinline__ float dot4(float4 a, float4 b) {
    return a.x * b.x + a.y * b.y + a.z * b.z + a.w * b.w;
}

__global__ __launch_bounds__(256) void attn_flash_k(
    const float* __restrict__ nf, const float* __restrict__ ef,
    const float* __restrict__ ntf,
    const unsigned char* __restrict__ maskp,
    const int* __restrict__ mode_p,
    const float* __restrict__ qk,
    float* __restrict__ wkv,
    float* __restrict__ invalf,
    float* __restrict__ attnw)
{
    const int lane = threadIdx.x & 63;
    const int wv   = threadIdx.x >> 6;
    const int b    = blockIdx.x * 4 + wv;
    const int mode = mode_p[0];

    int mv = 0;
    if (lane < NNB) {
        if (mode == 0)      mv = ((const int*)maskp)[(size_t)b * NNB + lane] != 0;
        else if (mode == 1) mv = maskp[(size_t)b * NNB + lane] != 0;
        else                mv = ((const float*)maskp)[(size_t)b * NNB + lane] != 0.f;
    }
    unsigned long long bal = __ballot(lane < NNB && mv);
    const int inv = ((bal & 0xFFFFFULL) == 0xFFFFFULL);
    if (inv && lane == 0) mv = 0;            // force-unmask neighbor 0
    if (lane == 0) invalf[b] = (float)inv;

    const float* qrow = qk + (size_t)b * 888;
    const float4 z4 = make_float4(0.f, 0.f, 0.f, 0.f);
    float4 q0a = *(const float4*)(qrow + lane * 4);
    float4 q1a = *(const float4*)(qrow + KD + lane * 4);
    float4 q0b = z4, q1b = z4;
    if (lane < 47) {
        q0b = *(const float4*)(qrow + (64 + lane) * 4);
        q1b = *(const float4*)(qrow + KD + (64 + lane) * 4);
    }

    const size_t rbase = (size_t)b * NNB;
    const float* pA;
    if (lane < 43) pA = nf + rbase * NF + lane * 4;
    else           pA = ef + rbase * EF + (lane - 43) * 4;
    const float* pB;
    int strideB;
    if (lane < 22) { pB = ef  + rbase * EF  + (21 + lane) * 4; strideB = EF;  }
    else           { pB = ntf + rbase * TF_ + (lane - 22) * 4; strideB = TF_; }

    const float scal = 0.08574929257125441f;  // 1/sqrt(136)
    float4 acc0a = z4, acc0b = z4, acc1a = z4, acc1b = z4;
    float m0 = -3.4e38f, m1 = -3.4e38f, s0 = 0.f, s1 = 0.f;
    float mys0 = 0.f, mys1 = 0.f;

#pragma unroll 5
    for (int n = 0; n < NNB; ++n) {
        float4 kA = *(const float4*)pA;
        pA += NF;
        float4 kB = z4;
        if (lane < 47) {
            kB = *(const float4*)pB;
            pB += strideB;
        }

        float p0 = dot4(q0a, kA) + dot4(q0b, kB);
        float p1 = dot4(q1a, kA) + dot4(q1b, kB);
#pragma unroll
        for (int off = 32; off; off >>= 1) {
            p0 += __shfl_xor(p0, off);
            p1 += __shfl_xor(p1, off);
        }

        const int mn = __shfl(mv, n);
        const float sc0 = mn ? -1e30f : p0 * scal;
        const float sc1 = mn ? -1e30f : p1 * scal;
        if (lane == n) { mys0 = sc0; mys1 = sc1; }

        {
            const float nm = fmaxf(m0, sc0);
            const float f  = expf(m0 - nm);
            const float p  = expf(sc0 - nm);
            s0 = s0 * f + p;
            acc0a.x = acc0a.x * f + p * kA.x;  acc0a.y = acc0a.y * f + p * kA.y;
            acc0a.z = acc0a.z * f + p * kA.z;  acc0a.w = acc0a.w * f + p * kA.w;
            acc0b.x = acc0b.x * f + p * kB.x;  acc0b.y = acc0b.y * f + p * kB.y;
            acc0b.z = acc0b.z * f + p * kB.z;  acc0b.w = acc0b.w * f + p * kB.w;
            m0 = nm;
        }
        {
            const float nm = fmaxf(m1, sc1);
            const float f  = expf(m1 - nm);
            const float p  = expf(sc1 - nm);
            s1 = s1 * f + p;
            acc1a.x = acc1a.x * f + p * kA.x;  acc1a.y = acc1a.y * f + p * kA.y;
            acc1a.z = acc1a.z * f + p * kA.z;  acc1a.w = acc1a.w * f + p * kA.w;
            acc1b.x = acc1b.x * f + p * kB.x;  acc1b.y = acc1b.y * f + p * kB.y;
            acc1b.z = acc1b.z * f + p * kB.z;  acc1b.w = acc1b.w * f + p * kB.w;
            m1 = nm;
        }
    }

    const float r0 = 1.f / s0;
    const float r1 = 1.f / s1;

    if (lane < NNB)
        attnw[(size_t)b * NNB + lane] =
            0.5f * (expf(mys0 - m0) * r0 + expf(mys1 - m1) * r1);

    float* wrow = wkv + (size_t)b * 888;
    float4 o;
    o.x = acc0a.x * r0; o.y = acc0a.y * r0; o.z = acc0a.z * r0; o.w = acc0a.w * r0;
    *(float4*)(wrow + lane * 4) = o;
    o.x = acc1a.x * r1; o.y = acc1a.y * r1; o.z = acc1a.z * r1; o.w = acc1a.w * r1;
    *(float4*)(wrow + KD + lane * 4) = o;
    if (lane < 47) {
        o.x = acc0b.x * r0; o.y = acc0b.y * r0; o.z = acc0b.z * r0; o.w = acc0b.w * r0;
        *(float4*)(wrow + (64 + lane) * 4) = o;
        o.x = acc1b.x * r1; o.y = acc1b.y * r1; o.z = acc1b.z * r1; o.w = acc1b.w * r1;
        *(float4*)(wrow + KD + (64 + lane) * 4) = o;
    }
}

// ---------------------------------------------------------------------------
extern "C" void kernel_launch(void* const* d_in, const int* in_sizes, int n_in,
                              void* d_out, int out_size, void* d_ws, size_t ws_size,
                              hipStream_t stream) {
    const float* src_node = (const float*)d_in[0];
    const float* src_time = (const float*)d_in[1];
    const float* nfp      = (const float*)d_in[2];
    const float* ntfp     = (const float*)d_in[3];  // neighbor_time
    const float* efp      = (const float*)d_in[4];  // edge
    const unsigned char* maskp = (const unsigned char*)d_in[5];
    const float* q_w   = (const float*)d_in[6];
    const float* k_w   = (const float*)d_in[7];
    const float* v_w   = (const float*)d_in[8];
    const float* q_b   = (const float*)d_in[9];
    // d_in[10] = k_b: no effect on outputs (uniform shift under softmax)
    const float* v_b   = (const float*)d_in[11];
    const float* out_w = (const float*)d_in[12];
    const float* out_b = (const float*)d_in[13];
    const float* m1_w  = (const float*)d_in[14];
    const float* m1_b  = (const float*)d_in[15];
    const float* m2_w  = (const float*)d_in[16];
    const float* m2_b  = (const float*)d_in[17];

    const int B = in_sizes[0] / NF;   // 32768

    // ws layout (aliasing, stream-ordered safe):
    //   flag [16] | Qb [B,272] (Q -> ctx -> hidden) | qkb [B,888] (qk -> wkv -> attn_out) | invb [B]
    float* ws   = (float*)d_ws;
    int*   flag = (int*)d_ws;
    float* Qb   = ws + 16;                       // [B,272]
    float* qkb  = Qb + (size_t)B * 272;          // [B,2,444]
    float* invb = qkb + (size_t)B * 888;         // [B]
    float* aob  = qkb;                           // [B,272] attn_out (reuse qkb after K5)
    float* hidb = Qb;                            // [B,172] hidden  (reuse Qb after K6)
    float* outp  = (float*)d_out;                // [B,172]
    float* attnw = outp + (size_t)B * OUT_D;     // [B,20]

    const int gm = B / 128;   // 256

    sniff_k<<<1, 256, 0, stream>>>(maskp, flag);

    // K1: Q = concat(src_node, src_time) @ q_w.T + q_b       [B,272]
    gemm_mfma_k<<<dim3(gm, 3), 256, 0, stream>>>(
        src_node, NF, NF, src_time, TF_,
        q_w, EDIM, 0, q_b, nullptr, 0, Qb, EDIM, EDIM, EDIM);

    // K2 (h=0,1): qk[:,h,:] = Q[:,h*136:(h+1)*136] @ k_w[h*136:,:]   [B,444]
    for (int h = 0; h < 2; ++h) {
        gemm_mfma_k<<<dim3(gm, 4), 256, 0, stream>>>(
            Qb + h * HD, HD, EDIM, nullptr, 0,
            k_w + (size_t)h * HD * KD, KD, 1, nullptr, nullptr, 0,
            qkb + h * KD, 888, KD, HD);
    }

    // K3: flash attention pass (wkv aliases qk; same-row read-then-write in-wave)
    attn_flash_k<<<B / 4, 256, 0, stream>>>(nfp, efp, ntfp, maskp, flag,
                                            qkb, qkb, invb, attnw);

    // K5 (h=0,1): ctx[:,h*136:] = wkv[:,h,:] @ v_w[h-part].T + v_b   (ctx = Qb)
    for (int h = 0; h < 2; ++h) {
        gemm_mfma_k<<<dim3(gm, 2), 256, 0, stream>>>(
            qkb + h * KD, KD, 888, nullptr, 0,
            v_w + (size_t)h * HD * KD, KD, 0, v_b + h * HD, nullptr, 0,
            Qb + h * HD, EDIM, HD, KD);
    }

    // K6: attn_out = ctx @ out_w.T + out_b, zeroed where invalid (-> qkb region)
    gemm_mfma_k<<<dim3(gm, 3), 256, 0, stream>>>(
        Qb, EDIM, EDIM, nullptr, 0,
        out_w, EDIM, 0, out_b, invb, 0, aob, EDIM, EDIM, EDIM);

    // K7: hidden = relu(concat(attn_out, src_node) @ m1_w.T + m1_b)  (-> Qb region)
    gemm_mfma_k<<<dim3(gm, 2), 256, 0, stream>>>(
        aob, EDIM, EDIM, src_node, NF,
        m1_w, KD, 0, m1_b, nullptr, 1, hidb, OUT_D, OUT_D, KD);

    // K8: out = hidden @ m2_w.T + m2_b
    gemm_mfma_k<<<dim3(gm, 2), 256, 0, stream>>>(
        hidb, OUT_D, OUT_D, nullptr, 0,
        m2_w, OUT_D, 0, m2_b, nullptr, 0, outp, OUT_D, OUT_D, OUT_D);
}